// Round 2
// baseline (666.561 us; speedup 1.0000x reference)
//
#include <hip/hip_runtime.h>

#define SXD 256
#define SYD 256
#define SZD 32
#define NTOTAL (4 * SXD * SYD * SZD)      // 8388608 cells
#define TABLE_BYTES ((size_t)NTOTAL * sizeof(int))
#define CIN 32
#define COUT 32
#define NK 27

// wt[t] with t = (k*CIN + ci)*COUT + co  <-  w[co][ci][k]  (w is (COUT,CIN,27) flat)
__global__ __launch_bounds__(256) void wt_transpose_kernel(const float* __restrict__ w,
                                                           float* __restrict__ wt) {
    int t = blockIdx.x * 256 + threadIdx.x;
    if (t >= NK * CIN * COUT) return;
    int co = t & 31;
    int ci = (t >> 5) & 31;
    int k  = t >> 10;
    wt[t] = w[(co * CIN + ci) * NK + k];
}

// indices are int32 on device (harness converts integer inputs to int32)
__global__ __launch_bounds__(256) void scatter_kernel(const int* __restrict__ idx,
                                                      int* __restrict__ table, int n) {
    int i = blockIdx.x * 256 + threadIdx.x;
    if (i >= n) return;
    int b = idx[4 * i + 0];
    int x = idx[4 * i + 1];
    int y = idx[4 * i + 2];
    int z = idx[4 * i + 3];
    int lin = ((b * SXD + x) * SYD + y) * SZD + z;
    table[lin] = i;
}

__global__ __launch_bounds__(256) void conv_kernel(
    const float* __restrict__ f, const int* __restrict__ idx,
    const float* __restrict__ wt, const float* __restrict__ bias,
    const int* __restrict__ table, float* __restrict__ out, int n) {
    int pt = blockIdx.x * 8 + (threadIdx.x >> 5);
    int co = threadIdx.x & 31;
    if (pt >= n) return;

    int b = idx[4 * pt + 0];
    int x = idx[4 * pt + 1];
    int y = idx[4 * pt + 2];
    int z = idx[4 * pt + 3];

    float acc = bias[co];

    int k = 0;
#pragma unroll
    for (int dx = -1; dx <= 1; ++dx) {
        int nx = x + dx;
        bool okx = ((unsigned)nx < SXD);
#pragma unroll
        for (int dy = -1; dy <= 1; ++dy) {
            int ny = y + dy;
            bool oky = okx && ((unsigned)ny < SYD);
            int rowbase = ((b * SXD + nx) * SYD + ny) * SZD;
#pragma unroll
            for (int dz = -1; dz <= 1; ++dz, ++k) {
                int nz = z + dz;
                if (!(oky && ((unsigned)nz < SZD))) continue;
                int nbr = table[rowbase + nz];
                if (nbr >= 0) {
                    const float4* fr = (const float4*)(f + (size_t)nbr * CIN);
                    const float* wk = wt + k * (CIN * COUT) + co;
#pragma unroll
                    for (int c4 = 0; c4 < 8; ++c4) {
                        float4 fv = fr[c4];
                        acc += fv.x * wk[(c4 * 4 + 0) * COUT];
                        acc += fv.y * wk[(c4 * 4 + 1) * COUT];
                        acc += fv.z * wk[(c4 * 4 + 2) * COUT];
                        acc += fv.w * wk[(c4 * 4 + 3) * COUT];
                    }
                }
            }
        }
    }
    out[(size_t)pt * COUT + co] = acc;
}

extern "C" void kernel_launch(void* const* d_in, const int* in_sizes, int n_in,
                              void* d_out, int out_size, void* d_ws, size_t ws_size,
                              hipStream_t stream) {
    const float* f        = (const float*)d_in[0];
    const int* idx        = (const int*)d_in[1];
    const float* w        = (const float*)d_in[2];
    const float* bias     = (const float*)d_in[3];
    float* out            = (float*)d_out;
    int n = in_sizes[0] / CIN;  // 400000

    int* table = (int*)d_ws;
    float* wt  = (float*)((char*)d_ws + TABLE_BYTES);

    // Workspace is re-poisoned before every launch: rebuild table each call.
    hipMemsetAsync(table, 0xFF, TABLE_BYTES, stream);
    wt_transpose_kernel<<<(NK * CIN * COUT + 255) / 256, 256, 0, stream>>>(w, wt);
    scatter_kernel<<<(n + 255) / 256, 256, 0, stream>>>(idx, table, n);
    conv_kernel<<<(n + 7) / 8, 256, 0, stream>>>(f, idx, wt, bias, table, out, n);
}

// Round 5
// 438.952 us; speedup vs baseline: 1.5185x; 1.5185x over previous
//
#include <hip/hip_runtime.h>

#define SXD 256
#define SYD 256
#define SZD 32
#define NTOTAL (4 * SXD * SYD * SZD)      // 8388608 cells
#define TABLE_BYTES ((size_t)NTOTAL * sizeof(int))
#define CIN 32
#define COUT 32
#define WT4_FLOATS (27 * 8 * 32 * 4)      // 27648 floats, 110 KB
#define NBR_STRIDE 32

// wt4[((k*8 + ci2)*32 + co)*4 + j] = w[co][ci2*4+j][k]   (w is (COUT,CIN,27) flat)
// i.e. lane `co` loads one float4 = weights for 4 consecutive ci at its co.
__global__ __launch_bounds__(256) void wt4_kernel(const float* __restrict__ w,
                                                  float* __restrict__ wt4) {
    int t = blockIdx.x * 256 + threadIdx.x;
    if (t >= WT4_FLOATS) return;
    int j   = t & 3;
    int co  = (t >> 2) & 31;
    int ci2 = (t >> 7) & 7;
    int k   = t >> 10;
    wt4[t] = w[(co * CIN + (ci2 * 4 + j)) * 27 + k];
}

__global__ __launch_bounds__(256) void scatter_kernel(const int* __restrict__ idx,
                                                      int* __restrict__ table, int n) {
    int i = blockIdx.x * 256 + threadIdx.x;
    if (i >= n) return;
    int b = idx[4 * i + 0];
    int x = idx[4 * i + 1];
    int y = idx[4 * i + 2];
    int z = idx[4 * i + 3];
    table[((b * SXD + x) * SYD + y) * SZD + z] = i;
}

// One thread per (point, slot): all probes independent -> latency fully hidden.
__global__ __launch_bounds__(256) void probe_kernel(const int* __restrict__ idx,
                                                    const int* __restrict__ table,
                                                    int* __restrict__ nbrs, int n) {
    int t = blockIdx.x * 256 + threadIdx.x;
    int p   = t >> 5;
    int off = t & 31;
    if (p >= n) return;
    int4 c = ((const int4*)idx)[p];     // b,x,y,z
    int nbr = -1;
    if (off < 27) {
        int dx = off / 9 - 1;
        int dy = (off / 3) % 3 - 1;
        int dz = off % 3 - 1;
        int nx = c.y + dx, ny = c.z + dy, nz = c.w + dz;
        if ((unsigned)nx < SXD && (unsigned)ny < SYD && (unsigned)nz < SZD)
            nbr = table[((c.x * SXD + nx) * SYD + ny) * SZD + nz];
    }
    nbrs[p * NBR_STRIDE + off] = nbr;
}

// Wave = 2 points (half-wave per point, lane = co). One coalesced load brings the
// 27-slot neighbor list; ballot -> mask; iterate only matches.
__global__ __launch_bounds__(256) void conv2_kernel(
    const float* __restrict__ f, const int* __restrict__ nbrs,
    const float* __restrict__ wt4, const float* __restrict__ bias,
    float* __restrict__ out, int n) {
    int wave = blockIdx.x * 4 + (threadIdx.x >> 6);
    int lane = threadIdx.x & 63;
    int half = lane >> 5;
    int co   = lane & 31;
    int p    = wave * 2 + half;
    bool valid = p < n;

    int m = -1;
    if (valid) m = nbrs[p * NBR_STRIDE + co];   // slot `co` (27..31 hold -1)
    unsigned long long ball = __ballot(m >= 0);
    unsigned mymask = (unsigned)(ball >> (half * 32));

    float acc = valid ? bias[co] : 0.0f;

    while (mymask) {
        int kk = __ffs(mymask) - 1;            // offset id 0..26
        mymask &= mymask - 1;
        int nbr = __shfl(m, (half << 5) + kk, 64);
        const float4* fr = (const float4*)(f + (size_t)nbr * CIN);
        const float4* wr = (const float4*)wt4 + kk * 256 + co;   // [k][ci2][co]
#pragma unroll
        for (int q = 0; q < 8; ++q) {
            float4 fv = fr[q];
            float4 wv = wr[q * 32];
            acc += fv.x * wv.x + fv.y * wv.y + fv.z * wv.z + fv.w * wv.w;
        }
    }
    if (valid) out[(size_t)p * COUT + co] = acc;
}

extern "C" void kernel_launch(void* const* d_in, const int* in_sizes, int n_in,
                              void* d_out, int out_size, void* d_ws, size_t ws_size,
                              hipStream_t stream) {
    const float* f    = (const float*)d_in[0];
    const int* idx    = (const int*)d_in[1];
    const float* w    = (const float*)d_in[2];
    const float* bias = (const float*)d_in[3];
    float* out        = (float*)d_out;
    int n = in_sizes[0] / CIN;  // 400000

    int*   table = (int*)d_ws;
    float* wt4   = (float*)((char*)d_ws + TABLE_BYTES);
    int*   nbrs  = (int*)((char*)d_ws + TABLE_BYTES + WT4_FLOATS * sizeof(float));

    // ws is re-poisoned before every launch: rebuild everything each call.
    hipMemsetAsync(table, 0xFF, TABLE_BYTES, stream);
    wt4_kernel<<<(WT4_FLOATS + 255) / 256, 256, 0, stream>>>(w, wt4);
    scatter_kernel<<<(n + 255) / 256, 256, 0, stream>>>(idx, table, n);
    probe_kernel<<<((size_t)n * 32 + 255) / 256, 256, 0, stream>>>(idx, table, nbrs, n);
    conv2_kernel<<<(n + 7) / 8, 256, 0, stream>>>(f, nbrs, wt4, bias, out, n);
}